// Round 8
// baseline (48.475 us; speedup 1.0000x reference)
//
#include <hip/hip_runtime.h>

#define IMG_W 1024
#define IMG_H 1024

typedef float f32x4 __attribute__((ext_vector_type(4)));
typedef int   i32x4 __attribute__((ext_vector_type(4)));

// One WAVE (64 lanes) per 128x128 tile; 2048 tiles = 2048 waves.
// 512 blocks x 256 threads (4 waves/block) = 2 blocks/CU, 8 waves/CU.
// ZERO block barriers: every wave fully independent -> no phase-locking,
// read/write/LDS work mixes machine-wide by construction.
__global__ __launch_bounds__(256, 2) void clahe_kernel(const float* __restrict__ img,
                                                       float* __restrict__ out) {
    const int tid  = blockIdx.x * 256 + threadIdx.x;
    const int tile = tid >> 6;            // 0..2047 (one tile per wave)
    const int lane = threadIdx.x & 63;
    const int wv   = threadIdx.x >> 6;    // wave id within block

    const int b  = tile >> 6;
    const int ty = (tile >> 3) & 7;
    const int tx = tile & 7;
    const size_t base = ((size_t)b * IMG_H + (size_t)ty * 128) * IMG_W + (size_t)tx * 128;

    __shared__ int   hist_s[4][256];      // per-wave private
    __shared__ float cdf_s[4][256];       // per-wave private
    int*   hist = hist_s[wv];
    float* cdf  = cdf_s[wv];

    // zero own hist. DS ops from a single wave execute in order on the DS
    // pipe -> later atomics see the zeros without any barrier.
    {
        i32x4 z = {0, 0, 0, 0};
        *reinterpret_cast<i32x4*>(&hist[lane << 2]) = z;
    }

    // lane covers cols (lane&31)*4, rows (lane>>5) + 2*j ; 64 f32x4 per lane.
    const size_t toff = (size_t)(lane >> 5) * IMG_W + ((lane & 31) << 2);
    const float* __restrict__ p = img + base + toff;
    float* __restrict__ d = out + base + toff;

    f32x4 vA[8], vB[8];                   // double-buffered load chunks
    unsigned int pk[8][8];                // packed 255-indices (static-indexed)

    #pragma unroll
    for (int j = 0; j < 8; ++j)
        vA[j] = *reinterpret_cast<const f32x4*>(p + (size_t)(2 * j) * IMG_W);

    // ---- Pass 1: histogram + stash lookup indices. No barriers.
    #pragma unroll
    for (int c = 0; c < 8; ++c) {
        f32x4* cur = (c & 1) ? vB : vA;   // c is compile-time after unroll
        f32x4* nxt = (c & 1) ? vA : vB;
        if (c < 7) {
            #pragma unroll
            for (int j = 0; j < 8; ++j)
                nxt[j] = *reinterpret_cast<const f32x4*>(
                    p + (size_t)((c + 1) * 16 + 2 * j) * IMG_W);
        }
        #pragma unroll
        for (int j = 0; j < 8; ++j) {
            const f32x4 v = cur[j];
            atomicAdd(&hist[min(255, (int)(v.x * 256.0f))], 1);
            atomicAdd(&hist[min(255, (int)(v.y * 256.0f))], 1);
            atomicAdd(&hist[min(255, (int)(v.z * 256.0f))], 1);
            atomicAdd(&hist[min(255, (int)(v.w * 256.0f))], 1);
            pk[c][j] = (unsigned int)min(255, (int)(v.x * 255.0f))
                     | ((unsigned int)min(255, (int)(v.y * 255.0f)) << 8)
                     | ((unsigned int)min(255, (int)(v.z * 255.0f)) << 16)
                     | ((unsigned int)min(255, (int)(v.w * 255.0f)) << 24);
        }
    }

    // ---- Wave-level clip + scan. All integer (exact):
    //   excess = 16384 - sum(min(h,128));  total = summin + excess = 16384.
    const i32x4 hq = *reinterpret_cast<const i32x4*>(&hist[lane << 2]);
    const int m0 = min(hq.x, 128), m1 = min(hq.y, 128);
    const int m2 = min(hq.z, 128), m3 = min(hq.w, 128);
    const int lsum = m0 + m1 + m2 + m3;
    int x = lsum;
    #pragma unroll
    for (int off = 1; off < 64; off <<= 1) {
        const int y = __shfl_up(x, off);
        if (lane >= off) x += y;
    }
    const int summin = __shfl(x, 63);
    const float e256 = (float)(16384 - summin) * (1.0f / 256.0f);
    const float inv  = 1.0f / 16384.0f;
    const int ex = x - lsum;              // exclusive prefix of min-part
    const int k0 = lane << 2;
    f32x4 cd;
    cd.x = ((float)(ex + m0)                 + (float)(k0 + 1) * e256) * inv;
    cd.y = ((float)(ex + m0 + m1)            + (float)(k0 + 2) * e256) * inv;
    cd.z = ((float)(ex + m0 + m1 + m2)       + (float)(k0 + 3) * e256) * inv;
    cd.w = ((float)(ex + m0 + m1 + m2 + m3)  + (float)(k0 + 4) * e256) * inv;
    *reinterpret_cast<f32x4*>(&cdf[k0]) = cd;

    // ---- Pass 2: pure LDS gather + NT store (DS in-order: gather sees cdf).
    #pragma unroll
    for (int c = 0; c < 8; ++c) {
        #pragma unroll
        for (int j = 0; j < 8; ++j) {
            const unsigned int u = pk[c][j];
            f32x4 o;
            o.x = cdf[u & 255u];
            o.y = cdf[(u >> 8) & 255u];
            o.z = cdf[(u >> 16) & 255u];
            o.w = cdf[u >> 24];
            __builtin_nontemporal_store(
                o, reinterpret_cast<f32x4*>(d + (size_t)(c * 16 + 2 * j) * IMG_W));
        }
    }
}

extern "C" void kernel_launch(void* const* d_in, const int* in_sizes, int n_in,
                              void* d_out, int out_size, void* d_ws, size_t ws_size,
                              hipStream_t stream) {
    const float* img = (const float*)d_in[0];
    float* out = (float*)d_out;
    clahe_kernel<<<512, 256, 0, stream>>>(img, out);
}

// Round 9
// 47.449 us; speedup vs baseline: 1.0216x; 1.0216x over previous
//
#include <hip/hip_runtime.h>

#define IMG_W 1024
#define IMG_H 1024

typedef float f32x4 __attribute__((ext_vector_type(4)));
typedef int   i32x4 __attribute__((ext_vector_type(4)));

// One BLOCK (128 threads = 2 waves) per 128x128 tile; 2048 blocks = 8/CU
// (16 waves/CU). Each wave histograms its half-tile into a private LDS
// histogram (in-order DS, no sync). ONE __syncthreads per tile; then each
// wave redundantly scans (integer, exact) and writes its OWN cdf copy, so
// the pass-2 gather needs no further sync. Blocks drift freely.
__global__ __launch_bounds__(128, 4) void clahe_kernel(const float* __restrict__ img,
                                                       float* __restrict__ out) {
    const int tile = blockIdx.x;          // 0..2047
    const int lane = threadIdx.x & 63;
    const int wv   = threadIdx.x >> 6;    // 0..1

    const int b  = tile >> 6;
    const int ty = (tile >> 3) & 7;
    const int tx = tile & 7;
    const size_t base = ((size_t)b * IMG_H + (size_t)ty * 128) * IMG_W + (size_t)tx * 128;

    __shared__ int   hist_s[2][256];      // per-wave private histograms
    __shared__ float cdf_s[2][256];       // per-wave private cdf copies
    int*   hist = hist_s[wv];
    float* cdf  = cdf_s[wv];

    // zero own hist (in-order DS: later atomics see zeros, no barrier)
    {
        i32x4 z = {0, 0, 0, 0};
        *reinterpret_cast<i32x4*>(&hist[lane << 2]) = z;
    }

    // wave wv covers rows [wv*64, wv*64+64). Lane: col4 = (lane&31)*4,
    // row = wv*64 + (lane>>5) + 2*j, j = 0..31.
    const size_t toff = ((size_t)(wv * 64 + (lane >> 5))) * IMG_W + ((lane & 31) << 2);
    const float* __restrict__ p = img + base + toff;
    float* __restrict__ d = out + base + toff;

    f32x4 vA[4], vB[4];                   // double-buffered load chunks
    unsigned int pk[32];                  // packed 255-indices (static-indexed)

    #pragma unroll
    for (int j = 0; j < 4; ++j)
        vA[j] = *reinterpret_cast<const f32x4*>(p + (size_t)(2 * j) * IMG_W);

    // ---- Pass 1: histogram + stash lookup indices. No barriers.
    #pragma unroll
    for (int c = 0; c < 8; ++c) {
        f32x4* cur = (c & 1) ? vB : vA;   // compile-time after unroll
        f32x4* nxt = (c & 1) ? vA : vB;
        if (c < 7) {
            #pragma unroll
            for (int j = 0; j < 4; ++j)
                nxt[j] = *reinterpret_cast<const f32x4*>(
                    p + (size_t)((c + 1) * 8 + 2 * j) * IMG_W);
        }
        #pragma unroll
        for (int j = 0; j < 4; ++j) {
            const f32x4 v = cur[j];
            atomicAdd(&hist[min(255, (int)(v.x * 256.0f))], 1);
            atomicAdd(&hist[min(255, (int)(v.y * 256.0f))], 1);
            atomicAdd(&hist[min(255, (int)(v.z * 256.0f))], 1);
            atomicAdd(&hist[min(255, (int)(v.w * 256.0f))], 1);
            pk[c * 4 + j] = (unsigned int)min(255, (int)(v.x * 255.0f))
                          | ((unsigned int)min(255, (int)(v.y * 255.0f)) << 8)
                          | ((unsigned int)min(255, (int)(v.z * 255.0f)) << 16)
                          | ((unsigned int)min(255, (int)(v.w * 255.0f)) << 24);
        }
    }

    // ---- the ONLY barrier: both waves' histograms complete
    __syncthreads();

    // ---- Wave-level clip + scan (redundant per wave; integer, exact):
    //   excess = 16384 - sum(min(h,128));  total = 16384.
    const i32x4 h0 = *reinterpret_cast<const i32x4*>(&hist_s[0][lane << 2]);
    const i32x4 h1 = *reinterpret_cast<const i32x4*>(&hist_s[1][lane << 2]);
    const int m0 = min(h0.x + h1.x, 128), m1 = min(h0.y + h1.y, 128);
    const int m2 = min(h0.z + h1.z, 128), m3 = min(h0.w + h1.w, 128);
    const int lsum = m0 + m1 + m2 + m3;
    int x = lsum;
    #pragma unroll
    for (int off = 1; off < 64; off <<= 1) {
        const int y = __shfl_up(x, off);
        if (lane >= off) x += y;
    }
    const int summin = __shfl(x, 63);
    const float e256 = (float)(16384 - summin) * (1.0f / 256.0f);
    const float inv  = 1.0f / 16384.0f;
    const int ex = x - lsum;              // exclusive prefix of min-part
    const int k0 = lane << 2;
    f32x4 cd;
    cd.x = ((float)(ex + m0)                + (float)(k0 + 1) * e256) * inv;
    cd.y = ((float)(ex + m0 + m1)           + (float)(k0 + 2) * e256) * inv;
    cd.z = ((float)(ex + m0 + m1 + m2)      + (float)(k0 + 3) * e256) * inv;
    cd.w = ((float)(ex + m0 + m1 + m2 + m3) + (float)(k0 + 4) * e256) * inv;
    *reinterpret_cast<f32x4*>(&cdf[k0]) = cd;   // own copy: gather below is
                                                // same-wave in-order DS.

    // ---- Pass 2: LDS gather from OWN cdf + NT store. No sync needed.
    #pragma unroll
    for (int i = 0; i < 32; ++i) {
        const unsigned int u = pk[i];
        f32x4 o;
        o.x = cdf[u & 255u];
        o.y = cdf[(u >> 8) & 255u];
        o.z = cdf[(u >> 16) & 255u];
        o.w = cdf[u >> 24];
        __builtin_nontemporal_store(
            o, reinterpret_cast<f32x4*>(d + (size_t)(2 * i) * IMG_W));
    }
}

extern "C" void kernel_launch(void* const* d_in, const int* in_sizes, int n_in,
                              void* d_out, int out_size, void* d_ws, size_t ws_size,
                              hipStream_t stream) {
    const float* img = (const float*)d_in[0];
    float* out = (float*)d_out;
    clahe_kernel<<<2048, 128, 0, stream>>>(img, out);
}